// Round 2
// baseline (1442.831 us; speedup 1.0000x reference)
//
#include <hip/hip_runtime.h>
#include <type_traits>

// ============================================================================
// CrossAttention pipeline, MI355X. Harness tensors are FP32; internal ws
// tensors are bf16. Geometry: B=2, C=256, H=W=256, NH=16, d=16, WS=8,
// hh=ww=32 -> 1024 windows/b.
// Identity: (attn@v1 + (1-attn)@v2)/2 = (attn@(v1-v2) + colsum(v2))/2
// R1 failed (absmax 4.56): ds_read_b64_tr_b16 addressing double-counted the
// per-lane offsets (guide semantics ambiguous). R2: no tr-read. X is staged
// TRANSPOSED into LDS ([px][k] pad-40) via scalar u16 scatter; B-fragments
// are then plain ds_read_b128, exactly mirroring the verified A-side layout
// (lane l: row/col = l&15, k = (l>>4)*8 + j, contiguous 8 bf16).
// GEMMs are HBM-bound (64-128MB fp32 in ~10-20us) so the scatter-write bank
// conflicts (~8-way on 16 u16 writes/thread/kstep) hide under memory.
// ============================================================================

#define HW 65536     // H*W
#define WID 256

typedef __attribute__((ext_vector_type(8))) short short8;
typedef __attribute__((ext_vector_type(8))) unsigned short ushort8;
typedef __attribute__((ext_vector_type(4))) float f32x4;

__device__ __forceinline__ float b2f(unsigned short u) {
  union { unsigned int i; float f; } c; c.i = ((unsigned int)u) << 16; return c.f;
}
__device__ __forceinline__ unsigned short f2b(float f) {
  union { float ff; unsigned int i; } c; c.ff = f;
  return (unsigned short)((c.i + 0x7FFFu + ((c.i >> 16) & 1u)) >> 16);
}

// ----------------------------------------------------------------------------
// MFMA projection GEMM: Out[m,p] = sum_k W[w_row0+m,k] * A[k,p] (A opt A1-A2).
// A: [256][65536] (float or bf16). W fp32 ld=256 (bf16-rounded on stage).
// Out: [256][65536] (float or bf16). Grid: (2 m-tiles, 512 px-tiles), 256 thr.
// Tile 128m x 128px, BK=32, 4 waves as 2x2, each wave 64x64 = 4x4 frags of
// v_mfma_f32_16x16x32_bf16.
// ----------------------------------------------------------------------------
template <typename AT, typename OT>
__global__ __launch_bounds__(256) void gemm_mfma(
    const AT* __restrict__ A1, const AT* __restrict__ A2,
    const float* __restrict__ Wt, int w_row0, OT* __restrict__ Out) {
  __shared__ __align__(16) unsigned short Wl[128 * 40];  // [m][k] bf16, pad 40
  __shared__ __align__(16) unsigned short Xl[128 * 40];  // [px][k] bf16, pad 40

  const int t = threadIdx.x;
  const int l = t & 63;
  const int wv = t >> 6;               // wave 0..3
  const int wm  = (wv >> 1) * 64;      // wave m offset within tile
  const int wpx = (wv & 1) * 64;       // wave px offset within tile
  const int m0  = blockIdx.x * 128;    // m tile (fastest -> X tile L2 reuse)
  const int hw0 = blockIdx.y * 128;    // pixel tile

  f32x4 acc[4][4];
#pragma unroll
  for (int a = 0; a < 4; ++a)
#pragma unroll
    for (int b = 0; b < 4; ++b) acc[a][b] = 0.f;

  // X staging: thread t reads k-row (t>>3), 16 px at (t&7)*16; writes
  // transposed into Xl[px][k].
  const int sk  = t >> 3;              // 0..31
  const int spx = (t & 7) * 16;        // 0..112

  // fragment read coords (A and B sides identical pattern)
  const int al  = l & 15;
  const int ak8 = (l >> 4) * 8;

  for (int k0 = 0; k0 < 256; k0 += 32) {
    // ---- stage X tile transposed (fp32 -> bf16, optionally A1-A2) ----
    {
      const size_t goff = (size_t)(k0 + sk) * HW + hw0 + spx;
      if constexpr (std::is_same_v<AT, float>) {
        const float4* p1 = (const float4*)(A1 + goff);
        float4 u0 = p1[0], u1 = p1[1], u2 = p1[2], u3 = p1[3];
        if (A2) {
          const float4* p2 = (const float4*)(A2 + goff);
          float4 w0 = p2[0], w1 = p2[1], w2 = p2[2], w3 = p2[3];
          u0.x -= w0.x; u0.y -= w0.y; u0.z -= w0.z; u0.w -= w0.w;
          u1.x -= w1.x; u1.y -= w1.y; u1.z -= w1.z; u1.w -= w1.w;
          u2.x -= w2.x; u2.y -= w2.y; u2.z -= w2.z; u2.w -= w2.w;
          u3.x -= w3.x; u3.y -= w3.y; u3.z -= w3.z; u3.w -= w3.w;
        }
        const float fa[16] = {u0.x, u0.y, u0.z, u0.w, u1.x, u1.y, u1.z, u1.w,
                              u2.x, u2.y, u2.z, u2.w, u3.x, u3.y, u3.z, u3.w};
#pragma unroll
        for (int i = 0; i < 16; ++i) Xl[(spx + i) * 40 + sk] = f2b(fa[i]);
      } else {
        const ushort8* p = (const ushort8*)(A1 + goff);
        ushort8 v0 = p[0], v1 = p[1];
#pragma unroll
        for (int i = 0; i < 8; ++i) {
          Xl[(spx + i) * 40 + sk]     = v0[i];
          Xl[(spx + 8 + i) * 40 + sk] = v1[i];
        }
      }
    }
    // ---- stage W tile (fp32 -> bf16), natural [m][k] ----
#pragma unroll
    for (int r = 0; r < 4; ++r) {
      const int idx = t + r * 256;
      const int row = idx >> 3;          // 0..127
      const int kq  = (idx & 7) * 4;     // 0..28
      float4 wv4 = *(const float4*)&Wt[(size_t)(w_row0 + m0 + row) * 256 + k0 + kq];
      unsigned short* d = &Wl[row * 40 + kq];
      d[0] = f2b(wv4.x); d[1] = f2b(wv4.y); d[2] = f2b(wv4.z); d[3] = f2b(wv4.w);
    }
    __syncthreads();

    // ---- fragments: plain ds_read_b128, A/B sides mirror-identical ----
    short8 af[4], bf[4];
#pragma unroll
    for (int a = 0; a < 4; ++a)
      af[a] = *(const short8*)&Wl[(wm + a * 16 + al) * 40 + ak8];
#pragma unroll
    for (int b = 0; b < 4; ++b)
      bf[b] = *(const short8*)&Xl[(wpx + b * 16 + al) * 40 + ak8];
#pragma unroll
    for (int a = 0; a < 4; ++a)
#pragma unroll
      for (int b = 0; b < 4; ++b)
        acc[a][b] = __builtin_amdgcn_mfma_f32_16x16x32_bf16(
            af[a], bf[b], acc[a][b], 0, 0, 0);
    __syncthreads();
  }

  // ---- epilogue: D col(px) = lane&15, row(m) = (lane>>4)*4 + reg ----
  const int orow = m0 + wm + (l >> 4) * 4;
  const int ocol = hw0 + wpx + al;
#pragma unroll
  for (int a = 0; a < 4; ++a)
#pragma unroll
    for (int b = 0; b < 4; ++b)
#pragma unroll
      for (int r = 0; r < 4; ++r) {
        const size_t o = (size_t)(orow + a * 16 + r) * HW + (ocol + b * 16);
        if constexpr (std::is_same_v<OT, float>) Out[o] = acc[a][b][r];
        else Out[o] = f2b(acc[a][b][r]);
      }
}

// ----------------------------------------------------------------------------
// Window column-sums of x2 (fp32): S[c][wy][wx] = sum over 8x8 window.
// ----------------------------------------------------------------------------
__global__ __launch_bounds__(256) void win_colsum(
    const float* __restrict__ X2, float* __restrict__ S) {
  int idx = blockIdx.x * 256 + threadIdx.x;   // 262144 per batch item
  int wx = idx & 31, wy = (idx >> 5) & 31, c = idx >> 10;
  const float* base = X2 + (size_t)c * HW + (size_t)(wy * 8) * WID + wx * 8;
  float s = 0.f;
#pragma unroll
  for (int iy = 0; iy < 8; ++iy) {
    float4 u0 = *(const float4*)(base + iy * WID);
    float4 u1 = *(const float4*)(base + iy * WID + 4);
    s += u0.x + u0.y + u0.z + u0.w + u1.x + u1.y + u1.z + u1.w;
  }
  S[idx] = s;
}

// ----------------------------------------------------------------------------
// V2S[w][c] = sum_k Wv[c,k] * S[k][w]  (Wv = qkv_w rows 512..767, fp32)
// ----------------------------------------------------------------------------
__global__ __launch_bounds__(256) void v2s_gemm(
    const float* __restrict__ S, const float* __restrict__ Wt,
    float* __restrict__ V2S) {
  __shared__ float sv[256];
  int wpos = blockIdx.x;          // 0..1023
  int c = threadIdx.x;
  sv[c] = S[(size_t)c * 1024 + wpos];
  __syncthreads();
  const float* wr = Wt + (size_t)(512 + c) * 256;
  float acc = 0.f;
#pragma unroll 4
  for (int k = 0; k < 256; k += 8) {
    float4 a = *(const float4*)&wr[k];
    float4 b = *(const float4*)&wr[k + 4];
    acc += a.x * sv[k]     + a.y * sv[k + 1]
         + a.z * sv[k + 2] + a.w * sv[k + 3]
         + b.x * sv[k + 4] + b.y * sv[k + 5]
         + b.z * sv[k + 6] + b.w * sv[k + 7];
  }
  V2S[(size_t)wpos * 256 + c] = acc;
}

// ----------------------------------------------------------------------------
// Windowed attention, one wave per (window, head). Lane = query position i.
// Q/K/VD are bf16 workspace; output O is fp32 (d_out plane).
// o[i,dd] = 0.5 * (sum_j softmax(q.k*0.25 + bias)[j] * vd[j,dd] + v2sum[dd])
// ----------------------------------------------------------------------------
__global__ __launch_bounds__(64) void attn_win(
    const unsigned short* __restrict__ Q, const unsigned short* __restrict__ K,
    const unsigned short* __restrict__ VD, const float* __restrict__ V2S,
    const float* __restrict__ RB, float* __restrict__ O) {
  __shared__ __align__(16) float4 ks4[64][5];  // 5th float4 pads row to 80 B
  __shared__ __align__(16) float4 vs4[64][5];
  __shared__ float bs[225];
  __shared__ float v2l[16];
  const int n = blockIdx.x;        // window 0..1023
  const int h = blockIdx.y;        // head
  const int wy = n >> 5, wx = n & 31;
  const int i = threadIdx.x;       // query position
  const int iy = i >> 3, ix = i & 7;
  const size_t base = (size_t)(h * 16) * HW + (size_t)(wy * 8) * WID + wx * 8;
  const size_t pix = (size_t)iy * WID + ix;

  float q[16];
#pragma unroll
  for (int q4 = 0; q4 < 4; ++q4) {
    float4 kv, vv;
    size_t a0 = base + (size_t)(q4 * 4 + 0) * HW + pix;
    size_t a1 = base + (size_t)(q4 * 4 + 1) * HW + pix;
    size_t a2 = base + (size_t)(q4 * 4 + 2) * HW + pix;
    size_t a3 = base + (size_t)(q4 * 4 + 3) * HW + pix;
    kv.x = b2f(K[a0]); kv.y = b2f(K[a1]); kv.z = b2f(K[a2]); kv.w = b2f(K[a3]);
    vv.x = b2f(VD[a0]); vv.y = b2f(VD[a1]); vv.z = b2f(VD[a2]); vv.w = b2f(VD[a3]);
    ks4[i][q4] = kv; vs4[i][q4] = vv;
    q[q4 * 4 + 0] = b2f(Q[a0]); q[q4 * 4 + 1] = b2f(Q[a1]);
    q[q4 * 4 + 2] = b2f(Q[a2]); q[q4 * 4 + 3] = b2f(Q[a3]);
  }
  for (int r = i; r < 225; r += 64) bs[r] = RB[r * 16 + h];
  if (i < 16) v2l[i] = V2S[(size_t)n * 256 + h * 16 + i];
  __syncthreads();

  float dots[64];
  float mx = -1e30f;
#pragma unroll
  for (int j = 0; j < 64; ++j) {
    const int jy = j >> 3, jx = j & 7;
    float s = 0.f;
#pragma unroll
    for (int q4 = 0; q4 < 4; ++q4) {
      float4 kv = ks4[j][q4];
      s = fmaf(q[q4 * 4 + 0], kv.x, s); s = fmaf(q[q4 * 4 + 1], kv.y, s);
      s = fmaf(q[q4 * 4 + 2], kv.z, s); s = fmaf(q[q4 * 4 + 3], kv.w, s);
    }
    s = s * 0.25f + bs[(iy - jy + 7) * 15 + (ix - jx + 7)];
    dots[j] = s; mx = fmaxf(mx, s);
  }
  float sum = 0.f;
#pragma unroll
  for (int j = 0; j < 64; ++j) { float e = __expf(dots[j] - mx); dots[j] = e; sum += e; }
  const float inv = 1.0f / sum;
  float o[16];
#pragma unroll
  for (int dd = 0; dd < 16; ++dd) o[dd] = v2l[dd];
#pragma unroll
  for (int j = 0; j < 64; ++j) {
    float p = dots[j] * inv;
#pragma unroll
    for (int q4 = 0; q4 < 4; ++q4) {
      float4 vv = vs4[j][q4];
      o[q4 * 4 + 0] = fmaf(p, vv.x, o[q4 * 4 + 0]);
      o[q4 * 4 + 1] = fmaf(p, vv.y, o[q4 * 4 + 1]);
      o[q4 * 4 + 2] = fmaf(p, vv.z, o[q4 * 4 + 2]);
      o[q4 * 4 + 3] = fmaf(p, vv.w, o[q4 * 4 + 3]);
    }
  }
#pragma unroll
  for (int dd = 0; dd < 16; ++dd)
    O[base + (size_t)dd * HW + pix] = 0.5f * o[dd];
}

// ----------------------------------------------------------------------------
// Directional pooling: ax (8x1 vertical) + ay (1x8 horizontal), both with
// reflect-pad of 1 at the end and zero-pad 3 (count_include_pad /8), then
// zero-pad one row/col -> P [c][257][257] (bf16 ws). Input O fp32.
// ----------------------------------------------------------------------------
__global__ __launch_bounds__(256) void pool_dir(
    const float* __restrict__ O, unsigned short* __restrict__ P) {
  const int y = blockIdx.x;       // 0..256
  const int c = blockIdx.y;       // 0..255
  const int x = threadIdx.x;      // 0..255
  unsigned short* prow = P + ((size_t)c * 257 + y) * 257;
  if (y == 256) { prow[x] = 0; if (x == 0) prow[256] = 0; return; }
  const float* op = O + (size_t)c * HW;
  float ax = 0.f;
#pragma unroll
  for (int u = -3; u <= 4; ++u) {
    int t = y + u;
    if (t >= 0 && t <= 256) { int yy = (t == 256) ? 254 : t; ax += op[yy * WID + x]; }
  }
  const float* orow = op + (size_t)y * WID;
  float ay = 0.f;
#pragma unroll
  for (int u = -3; u <= 4; ++u) {
    int t = x + u;
    if (t >= 0 && t <= 256) { int xx = (t == 256) ? 254 : t; ay += orow[xx]; }
  }
  prow[x] = f2b(0.125f * (ax + ay));
  if (x == 0) prow[256] = 0;
}

// ----------------------------------------------------------------------------
// 8x8 depthwise conv (pad 3, zero) over P [c][257][257] bf16 + BN -> bf16 out.
// 64x64 output tile per block, input tile (71x71 + halo) staged in LDS.
// ----------------------------------------------------------------------------
__global__ __launch_bounds__(256) void dwconv_bn(
    const unsigned short* __restrict__ P, const float* __restrict__ DW,
    const float* __restrict__ G, const float* __restrict__ Bt,
    const float* __restrict__ Mn, const float* __restrict__ Vr,
    unsigned short* __restrict__ Out) {
  __shared__ float tile[71 * 72];
  __shared__ float wk[64];
  const int c = blockIdx.y;
  const int ty = (blockIdx.x >> 2) * 64, tx = (blockIdx.x & 3) * 64;
  const int t = threadIdx.x;
  if (t < 64) wk[t] = DW[c * 64 + t];
  const unsigned short* pp = P + (size_t)c * 66049;
  for (int e = t; e < 71 * 71; e += 256) {
    int iy = e / 71, ixx = e - iy * 71;
    int gy = ty + iy - 3, gx = tx + ixx - 3;
    float v = 0.f;
    if (gy >= 0 && gy < 257 && gx >= 0 && gx < 257) v = b2f(pp[(size_t)gy * 257 + gx]);
    tile[iy * 72 + ixx] = v;
  }
  __syncthreads();
  const int ox0 = (t & 15) * 4, oy0 = (t >> 4) * 4;
  float acc[4][4];
#pragma unroll
  for (int r = 0; r < 4; ++r)
#pragma unroll
    for (int cc = 0; cc < 4; ++cc) acc[r][cc] = 0.f;
  for (int ky = 0; ky < 8; ++ky) {
#pragma unroll
    for (int r = 0; r < 4; ++r) {
      const float* row = &tile[(oy0 + r + ky) * 72 + ox0];
      float rv[11];
#pragma unroll
      for (int u = 0; u < 11; ++u) rv[u] = row[u];
#pragma unroll
      for (int kx = 0; kx < 8; ++kx) {
        float wv = wk[ky * 8 + kx];
        acc[r][0] = fmaf(rv[kx + 0], wv, acc[r][0]);
        acc[r][1] = fmaf(rv[kx + 1], wv, acc[r][1]);
        acc[r][2] = fmaf(rv[kx + 2], wv, acc[r][2]);
        acc[r][3] = fmaf(rv[kx + 3], wv, acc[r][3]);
      }
    }
  }
  const float inv = G[c] * rsqrtf(Vr[c] + 1e-5f);
  const float mu = Mn[c], bb = Bt[c];
#pragma unroll
  for (int r = 0; r < 4; ++r) {
    unsigned short* dst = Out + (size_t)c * HW + (size_t)(ty + oy0 + r) * WID + (tx + ox0);
#pragma unroll
    for (int cc = 0; cc < 4; ++cc) dst[cc] = f2b((acc[r][cc] - mu) * inv + bb);
  }
}

// ----------------------------------------------------------------------------
extern "C" void kernel_launch(void* const* d_in, const int* in_sizes, int n_in,
                              void* d_out, int out_size, void* d_ws, size_t ws_size,
                              hipStream_t stream) {
  const float* x1   = (const float*)d_in[0];
  const float* x2   = (const float*)d_in[1];
  const float* qkvw = (const float*)d_in[2];
  const float* relb = (const float*)d_in[3];
  const float* dww  = (const float*)d_in[4];
  const float* g    = (const float*)d_in[5];
  const float* be   = (const float*)d_in[6];
  const float* mn   = (const float*)d_in[7];
  const float* vr   = (const float*)d_in[8];
  const float* pww  = (const float*)d_in[9];
  float* out = (float*)d_out;

  const size_t PLANE = (size_t)256 * HW;
  // ws layout (bf16 intermediates, reused per batch item sequentially):
  //   vd [16777216] | qb/P [16908544] | kb/dcbn [16777216] | S,V2S f32 [2x262144]
  unsigned short* vd = (unsigned short*)d_ws;
  unsigned short* qb = vd + 16777216;          // q, later reused as pooled P
  unsigned short* kb = qb + 16908544;          // k, later reused as dwconv+BN out
  float* S   = (float*)(kb + 16777216);
  float* V2S = S + 262144;

  for (int b = 0; b < 2; ++b) {
    const float* x1b = x1 + (size_t)b * PLANE;
    const float* x2b = x2 + (size_t)b * PLANE;
    float* ob = out + (size_t)b * PLANE;

    gemm_mfma<float, unsigned short><<<dim3(2, 512), dim3(256), 0, stream>>>(
        x1b, nullptr, qkvw, 0, qb);
    gemm_mfma<float, unsigned short><<<dim3(2, 512), dim3(256), 0, stream>>>(
        x2b, nullptr, qkvw, 256, kb);
    gemm_mfma<float, unsigned short><<<dim3(2, 512), dim3(256), 0, stream>>>(
        x1b, x2b, qkvw, 512, vd);
    win_colsum<<<dim3(1024), dim3(256), 0, stream>>>(x2b, S);
    v2s_gemm<<<dim3(1024), dim3(256), 0, stream>>>(S, qkvw, V2S);
    attn_win<<<dim3(1024, 16), dim3(64), 0, stream>>>(qb, kb, vd, V2S, relb, ob);
    pool_dir<<<dim3(257, 256), dim3(256), 0, stream>>>(ob, qb);   // P -> qb
    dwconv_bn<<<dim3(16, 256), dim3(256), 0, stream>>>(qb, dww, g, be, mn, vr, kb);
    gemm_mfma<unsigned short, float><<<dim3(2, 512), dim3(256), 0, stream>>>(
        kb, nullptr, pww, 0, ob);
  }
}

// Round 3
// 1220.379 us; speedup vs baseline: 1.1823x; 1.1823x over previous
//
#include <hip/hip_runtime.h>
#include <type_traits>

// ============================================================================
// CrossAttention pipeline, MI355X. Harness tensors are FP32; internal ws
// tensors are bf16. Geometry: B=2, C=256, H=W=256, NH=16, d=16, WS=8,
// hh=ww=32 -> 1024 windows/b.
// Identity: (attn@v1 + (1-attn)@v2)/2 = (attn@(v1-v2) + colsum(v2))/2
// R2 (1442.8us, pass): MFMA GEMM w/ transposed-LDS X staging.
// R3: pool_dir was top dispatch (178us x2, 21% HBM, 4x over-fetch from
// XCD-scattered vertical halos + 1 px/thread latency-bound structure).
//   - band-tiled rewrite: block = (32-row band, channel); <=39 halo rows
//     staged once in LDS (39KB, 4 blocks/CU); 32 outputs/thread from LDS.
//   - attn output O now bf16, written IN-PLACE over vd (per-thread RAW only,
//     data-dependent through softmax -> safe; __restrict__ dropped there).
//     Saves 128MB fp32 -> 64MB bf16 O traffic per batch item.
// ============================================================================

#define HW 65536     // H*W
#define WID 256

typedef __attribute__((ext_vector_type(8))) short short8;
typedef __attribute__((ext_vector_type(8))) unsigned short ushort8;
typedef __attribute__((ext_vector_type(4))) float f32x4;

__device__ __forceinline__ float b2f(unsigned short u) {
  union { unsigned int i; float f; } c; c.i = ((unsigned int)u) << 16; return c.f;
}
__device__ __forceinline__ unsigned short f2b(float f) {
  union { float ff; unsigned int i; } c; c.ff = f;
  return (unsigned short)((c.i + 0x7FFFu + ((c.i >> 16) & 1u)) >> 16);
}

// ----------------------------------------------------------------------------
// MFMA projection GEMM: Out[m,p] = sum_k W[w_row0+m,k] * A[k,p] (A opt A1-A2).
// A: [256][65536] (float or bf16). W fp32 ld=256 (bf16-rounded on stage).
// Out: [256][65536] (float or bf16). Grid: (2 m-tiles, 512 px-tiles), 256 thr.
// Tile 128m x 128px, BK=32, 4 waves as 2x2, each wave 64x64 = 4x4 frags of
// v_mfma_f32_16x16x32_bf16.
// ----------------------------------------------------------------------------
template <typename AT, typename OT>
__global__ __launch_bounds__(256) void gemm_mfma(
    const AT* __restrict__ A1, const AT* __restrict__ A2,
    const float* __restrict__ Wt, int w_row0, OT* __restrict__ Out) {
  __shared__ __align__(16) unsigned short Wl[128 * 40];  // [m][k] bf16, pad 40
  __shared__ __align__(16) unsigned short Xl[128 * 40];  // [px][k] bf16, pad 40

  const int t = threadIdx.x;
  const int l = t & 63;
  const int wv = t >> 6;               // wave 0..3
  const int wm  = (wv >> 1) * 64;      // wave m offset within tile
  const int wpx = (wv & 1) * 64;       // wave px offset within tile
  const int m0  = blockIdx.x * 128;    // m tile (fastest -> X tile L2 reuse)
  const int hw0 = blockIdx.y * 128;    // pixel tile

  f32x4 acc[4][4];
#pragma unroll
  for (int a = 0; a < 4; ++a)
#pragma unroll
    for (int b = 0; b < 4; ++b) acc[a][b] = 0.f;

  // X staging: thread t reads k-row (t>>3), 16 px at (t&7)*16; writes
  // transposed into Xl[px][k].
  const int sk  = t >> 3;              // 0..31
  const int spx = (t & 7) * 16;        // 0..112

  // fragment read coords (A and B sides identical pattern)
  const int al  = l & 15;
  const int ak8 = (l >> 4) * 8;

  for (int k0 = 0; k0 < 256; k0 += 32) {
    // ---- stage X tile transposed (fp32 -> bf16, optionally A1-A2) ----
    {
      const size_t goff = (size_t)(k0 + sk) * HW + hw0 + spx;
      if constexpr (std::is_same_v<AT, float>) {
        const float4* p1 = (const float4*)(A1 + goff);
        float4 u0 = p1[0], u1 = p1[1], u2 = p1[2], u3 = p1[3];
        if (A2) {
          const float4* p2 = (const float4*)(A2 + goff);
          float4 w0 = p2[0], w1 = p2[1], w2 = p2[2], w3 = p2[3];
          u0.x -= w0.x; u0.y -= w0.y; u0.z -= w0.z; u0.w -= w0.w;
          u1.x -= w1.x; u1.y -= w1.y; u1.z -= w1.z; u1.w -= w1.w;
          u2.x -= w2.x; u2.y -= w2.y; u2.z -= w2.z; u2.w -= w2.w;
          u3.x -= w3.x; u3.y -= w3.y; u3.z -= w3.z; u3.w -= w3.w;
        }
        const float fa[16] = {u0.x, u0.y, u0.z, u0.w, u1.x, u1.y, u1.z, u1.w,
                              u2.x, u2.y, u2.z, u2.w, u3.x, u3.y, u3.z, u3.w};
#pragma unroll
        for (int i = 0; i < 16; ++i) Xl[(spx + i) * 40 + sk] = f2b(fa[i]);
      } else {
        const ushort8* p = (const ushort8*)(A1 + goff);
        ushort8 v0 = p[0], v1 = p[1];
#pragma unroll
        for (int i = 0; i < 8; ++i) {
          Xl[(spx + i) * 40 + sk]     = v0[i];
          Xl[(spx + 8 + i) * 40 + sk] = v1[i];
        }
      }
    }
    // ---- stage W tile (fp32 -> bf16), natural [m][k] ----
#pragma unroll
    for (int r = 0; r < 4; ++r) {
      const int idx = t + r * 256;
      const int row = idx >> 3;          // 0..127
      const int kq  = (idx & 7) * 4;     // 0..28
      float4 wv4 = *(const float4*)&Wt[(size_t)(w_row0 + m0 + row) * 256 + k0 + kq];
      unsigned short* d = &Wl[row * 40 + kq];
      d[0] = f2b(wv4.x); d[1] = f2b(wv4.y); d[2] = f2b(wv4.z); d[3] = f2b(wv4.w);
    }
    __syncthreads();

    // ---- fragments: plain ds_read_b128, A/B sides mirror-identical ----
    short8 af[4], bf[4];
#pragma unroll
    for (int a = 0; a < 4; ++a)
      af[a] = *(const short8*)&Wl[(wm + a * 16 + al) * 40 + ak8];
#pragma unroll
    for (int b = 0; b < 4; ++b)
      bf[b] = *(const short8*)&Xl[(wpx + b * 16 + al) * 40 + ak8];
#pragma unroll
    for (int a = 0; a < 4; ++a)
#pragma unroll
      for (int b = 0; b < 4; ++b)
        acc[a][b] = __builtin_amdgcn_mfma_f32_16x16x32_bf16(
            af[a], bf[b], acc[a][b], 0, 0, 0);
    __syncthreads();
  }

  // ---- epilogue: D col(px) = lane&15, row(m) = (lane>>4)*4 + reg ----
  const int orow = m0 + wm + (l >> 4) * 4;
  const int ocol = hw0 + wpx + al;
#pragma unroll
  for (int a = 0; a < 4; ++a)
#pragma unroll
    for (int b = 0; b < 4; ++b)
#pragma unroll
      for (int r = 0; r < 4; ++r) {
        const size_t o = (size_t)(orow + a * 16 + r) * HW + (ocol + b * 16);
        if constexpr (std::is_same_v<OT, float>) Out[o] = acc[a][b][r];
        else Out[o] = f2b(acc[a][b][r]);
      }
}

// ----------------------------------------------------------------------------
// Window column-sums of x2 (fp32): S[c][wy][wx] = sum over 8x8 window.
// ----------------------------------------------------------------------------
__global__ __launch_bounds__(256) void win_colsum(
    const float* __restrict__ X2, float* __restrict__ S) {
  int idx = blockIdx.x * 256 + threadIdx.x;   // 262144 per batch item
  int wx = idx & 31, wy = (idx >> 5) & 31, c = idx >> 10;
  const float* base = X2 + (size_t)c * HW + (size_t)(wy * 8) * WID + wx * 8;
  float s = 0.f;
#pragma unroll
  for (int iy = 0; iy < 8; ++iy) {
    float4 u0 = *(const float4*)(base + iy * WID);
    float4 u1 = *(const float4*)(base + iy * WID + 4);
    s += u0.x + u0.y + u0.z + u0.w + u1.x + u1.y + u1.z + u1.w;
  }
  S[idx] = s;
}

// ----------------------------------------------------------------------------
// V2S[w][c] = sum_k Wv[c,k] * S[k][w]  (Wv = qkv_w rows 512..767, fp32)
// ----------------------------------------------------------------------------
__global__ __launch_bounds__(256) void v2s_gemm(
    const float* __restrict__ S, const float* __restrict__ Wt,
    float* __restrict__ V2S) {
  __shared__ float sv[256];
  int wpos = blockIdx.x;          // 0..1023
  int c = threadIdx.x;
  sv[c] = S[(size_t)c * 1024 + wpos];
  __syncthreads();
  const float* wr = Wt + (size_t)(512 + c) * 256;
  float acc = 0.f;
#pragma unroll 4
  for (int k = 0; k < 256; k += 8) {
    float4 a = *(const float4*)&wr[k];
    float4 b = *(const float4*)&wr[k + 4];
    acc += a.x * sv[k]     + a.y * sv[k + 1]
         + a.z * sv[k + 2] + a.w * sv[k + 3]
         + b.x * sv[k + 4] + b.y * sv[k + 5]
         + b.z * sv[k + 6] + b.w * sv[k + 7];
  }
  V2S[(size_t)wpos * 256 + c] = acc;
}

// ----------------------------------------------------------------------------
// Windowed attention, one wave per (window, head). Lane = query position i.
// Q/K/VD bf16 ws; output O bf16, written IN-PLACE over VD (per-thread RAW
// only: thread i reads exactly the cells it later writes, and the stored
// value data-depends on those reads; blocks own disjoint regions).
// o[i,dd] = 0.5 * (sum_j softmax(q.k*0.25 + bias)[j] * vd[j,dd] + v2sum[dd])
// ----------------------------------------------------------------------------
__global__ __launch_bounds__(64) void attn_win(
    const unsigned short* __restrict__ Q, const unsigned short* __restrict__ K,
    const unsigned short* VD, const float* __restrict__ V2S,
    const float* __restrict__ RB, unsigned short* O) {
  __shared__ __align__(16) float4 ks4[64][5];  // 5th float4 pads row to 80 B
  __shared__ __align__(16) float4 vs4[64][5];
  __shared__ float bs[225];
  __shared__ float v2l[16];
  const int n = blockIdx.x;        // window 0..1023
  const int h = blockIdx.y;        // head
  const int wy = n >> 5, wx = n & 31;
  const int i = threadIdx.x;       // query position
  const int iy = i >> 3, ix = i & 7;
  const size_t base = (size_t)(h * 16) * HW + (size_t)(wy * 8) * WID + wx * 8;
  const size_t pix = (size_t)iy * WID + ix;

  float q[16];
#pragma unroll
  for (int q4 = 0; q4 < 4; ++q4) {
    float4 kv, vv;
    size_t a0 = base + (size_t)(q4 * 4 + 0) * HW + pix;
    size_t a1 = base + (size_t)(q4 * 4 + 1) * HW + pix;
    size_t a2 = base + (size_t)(q4 * 4 + 2) * HW + pix;
    size_t a3 = base + (size_t)(q4 * 4 + 3) * HW + pix;
    kv.x = b2f(K[a0]); kv.y = b2f(K[a1]); kv.z = b2f(K[a2]); kv.w = b2f(K[a3]);
    vv.x = b2f(VD[a0]); vv.y = b2f(VD[a1]); vv.z = b2f(VD[a2]); vv.w = b2f(VD[a3]);
    ks4[i][q4] = kv; vs4[i][q4] = vv;
    q[q4 * 4 + 0] = b2f(Q[a0]); q[q4 * 4 + 1] = b2f(Q[a1]);
    q[q4 * 4 + 2] = b2f(Q[a2]); q[q4 * 4 + 3] = b2f(Q[a3]);
  }
  for (int r = i; r < 225; r += 64) bs[r] = RB[r * 16 + h];
  if (i < 16) v2l[i] = V2S[(size_t)n * 256 + h * 16 + i];
  __syncthreads();

  float dots[64];
  float mx = -1e30f;
#pragma unroll
  for (int j = 0; j < 64; ++j) {
    const int jy = j >> 3, jx = j & 7;
    float s = 0.f;
#pragma unroll
    for (int q4 = 0; q4 < 4; ++q4) {
      float4 kv = ks4[j][q4];
      s = fmaf(q[q4 * 4 + 0], kv.x, s); s = fmaf(q[q4 * 4 + 1], kv.y, s);
      s = fmaf(q[q4 * 4 + 2], kv.z, s); s = fmaf(q[q4 * 4 + 3], kv.w, s);
    }
    s = s * 0.25f + bs[(iy - jy + 7) * 15 + (ix - jx + 7)];
    dots[j] = s; mx = fmaxf(mx, s);
  }
  float sum = 0.f;
#pragma unroll
  for (int j = 0; j < 64; ++j) { float e = __expf(dots[j] - mx); dots[j] = e; sum += e; }
  const float inv = 1.0f / sum;
  float o[16];
#pragma unroll
  for (int dd = 0; dd < 16; ++dd) o[dd] = v2l[dd];
#pragma unroll
  for (int j = 0; j < 64; ++j) {
    float p = dots[j] * inv;
#pragma unroll
    for (int q4 = 0; q4 < 4; ++q4) {
      float4 vv = vs4[j][q4];
      o[q4 * 4 + 0] = fmaf(p, vv.x, o[q4 * 4 + 0]);
      o[q4 * 4 + 1] = fmaf(p, vv.y, o[q4 * 4 + 1]);
      o[q4 * 4 + 2] = fmaf(p, vv.z, o[q4 * 4 + 2]);
      o[q4 * 4 + 3] = fmaf(p, vv.w, o[q4 * 4 + 3]);
    }
  }
#pragma unroll
  for (int dd = 0; dd < 16; ++dd)
    O[base + (size_t)dd * HW + pix] = f2b(0.5f * o[dd]);
}

// ----------------------------------------------------------------------------
// Directional pooling, band-tiled: block = (32-row band, channel). Stage the
// <=39 halo rows of O (bf16) once into LDS as f32; each thread computes 32
// outputs (vertical 8-win branch is wave-uniform; LDS reads conflict-free).
// ax: 8x1 sum over rows y-3..y+4, zero outside [0,256], reflect 256->254.
// ay: 1x8 sum over cols, same rule. P[c][257][257] bf16, last row/col zero.
// ----------------------------------------------------------------------------
__global__ __launch_bounds__(256) void pool_dir(
    const unsigned short* __restrict__ O, unsigned short* __restrict__ P) {
  __shared__ float tile[39][256];
  const int bnd = blockIdx.x;     // 0..7 (32-row band)
  const int c = blockIdx.y;       // 0..255
  const int x = threadIdx.x;      // 0..255
  const int y0 = bnd * 32;
  const int r0 = (y0 >= 3) ? y0 - 3 : 0;
  const int rmax = (y0 + 35 <= 255) ? (y0 + 35) : 255;
  const int nrows = rmax - r0 + 1;          // <= 39
  const unsigned short* op = O + (size_t)c * HW + (size_t)r0 * WID;
  for (int idx = threadIdx.x; idx < nrows * 32; idx += 256) {
    const int r = idx >> 5, ch = (idx & 31) * 8;
    ushort8 v = *(const ushort8*)(op + (size_t)r * WID + ch);
    float4 f0 = make_float4(b2f(v[0]), b2f(v[1]), b2f(v[2]), b2f(v[3]));
    float4 f1 = make_float4(b2f(v[4]), b2f(v[5]), b2f(v[6]), b2f(v[7]));
    *(float4*)&tile[r][ch] = f0;
    *(float4*)&tile[r][ch + 4] = f1;
  }
  __syncthreads();
  unsigned short* prow = P + ((size_t)c * 257 + y0) * 257;
  for (int yy = 0; yy < 32; ++yy) {
    const int y = y0 + yy;
    float ax = 0.f;
#pragma unroll
    for (int u = -3; u <= 4; ++u) {
      int t = y + u;                         // uniform across wave
      if (t >= 0 && t <= 256) { int ph = (t == 256) ? 254 : t; ax += tile[ph - r0][x]; }
    }
    float ay = 0.f;
    const float* row = &tile[y - r0][0];
#pragma unroll
    for (int u = -3; u <= 4; ++u) {
      int t = x + u;
      if (t >= 0 && t <= 256) { int xx = (t == 256) ? 254 : t; ay += row[xx]; }
    }
    prow[x] = f2b(0.125f * (ax + ay));
    if (x == 0) prow[256] = 0;
    prow += 257;
  }
  if (bnd == 7) {                            // zero row y = 256
    unsigned short* zr = P + ((size_t)c * 257 + 256) * 257;
    zr[x] = 0;
    if (x == 0) zr[256] = 0;
  }
}

// ----------------------------------------------------------------------------
// 8x8 depthwise conv (pad 3, zero) over P [c][257][257] bf16 + BN -> bf16 out.
// 64x64 output tile per block, input tile (71x71 + halo) staged in LDS.
// ----------------------------------------------------------------------------
__global__ __launch_bounds__(256) void dwconv_bn(
    const unsigned short* __restrict__ P, const float* __restrict__ DW,
    const float* __restrict__ G, const float* __restrict__ Bt,
    const float* __restrict__ Mn, const float* __restrict__ Vr,
    unsigned short* __restrict__ Out) {
  __shared__ float tile[71 * 72];
  __shared__ float wk[64];
  const int c = blockIdx.y;
  const int ty = (blockIdx.x >> 2) * 64, tx = (blockIdx.x & 3) * 64;
  const int t = threadIdx.x;
  if (t < 64) wk[t] = DW[c * 64 + t];
  const unsigned short* pp = P + (size_t)c * 66049;
  for (int e = t; e < 71 * 71; e += 256) {
    int iy = e / 71, ixx = e - iy * 71;
    int gy = ty + iy - 3, gx = tx + ixx - 3;
    float v = 0.f;
    if (gy >= 0 && gy < 257 && gx >= 0 && gx < 257) v = b2f(pp[(size_t)gy * 257 + gx]);
    tile[iy * 72 + ixx] = v;
  }
  __syncthreads();
  const int ox0 = (t & 15) * 4, oy0 = (t >> 4) * 4;
  float acc[4][4];
#pragma unroll
  for (int r = 0; r < 4; ++r)
#pragma unroll
    for (int cc = 0; cc < 4; ++cc) acc[r][cc] = 0.f;
  for (int ky = 0; ky < 8; ++ky) {
#pragma unroll
    for (int r = 0; r < 4; ++r) {
      const float* row = &tile[(oy0 + r + ky) * 72 + ox0];
      float rv[11];
#pragma unroll
      for (int u = 0; u < 11; ++u) rv[u] = row[u];
#pragma unroll
      for (int kx = 0; kx < 8; ++kx) {
        float wv = wk[ky * 8 + kx];
        acc[r][0] = fmaf(rv[kx + 0], wv, acc[r][0]);
        acc[r][1] = fmaf(rv[kx + 1], wv, acc[r][1]);
        acc[r][2] = fmaf(rv[kx + 2], wv, acc[r][2]);
        acc[r][3] = fmaf(rv[kx + 3], wv, acc[r][3]);
      }
    }
  }
  const float inv = G[c] * rsqrtf(Vr[c] + 1e-5f);
  const float mu = Mn[c], bb = Bt[c];
#pragma unroll
  for (int r = 0; r < 4; ++r) {
    unsigned short* dst = Out + (size_t)c * HW + (size_t)(ty + oy0 + r) * WID + (tx + ox0);
#pragma unroll
    for (int cc = 0; cc < 4; ++cc) dst[cc] = f2b((acc[r][cc] - mu) * inv + bb);
  }
}

// ----------------------------------------------------------------------------
extern "C" void kernel_launch(void* const* d_in, const int* in_sizes, int n_in,
                              void* d_out, int out_size, void* d_ws, size_t ws_size,
                              hipStream_t stream) {
  const float* x1   = (const float*)d_in[0];
  const float* x2   = (const float*)d_in[1];
  const float* qkvw = (const float*)d_in[2];
  const float* relb = (const float*)d_in[3];
  const float* dww  = (const float*)d_in[4];
  const float* g    = (const float*)d_in[5];
  const float* be   = (const float*)d_in[6];
  const float* mn   = (const float*)d_in[7];
  const float* vr   = (const float*)d_in[8];
  const float* pww  = (const float*)d_in[9];
  float* out = (float*)d_out;

  const size_t PLANE = (size_t)256 * HW;
  // ws layout (bf16 intermediates, reused per batch item sequentially):
  //   vd/O [16777216] | qb/P [16908544] | kb/dcbn [16777216] | S,V2S f32
  unsigned short* vd = (unsigned short*)d_ws;  // v1-v2, then attn O (in-place)
  unsigned short* qb = vd + 16777216;          // q, later reused as pooled P
  unsigned short* kb = qb + 16908544;          // k, later reused as dwconv+BN out
  float* S   = (float*)(kb + 16777216);
  float* V2S = S + 262144;

  for (int b = 0; b < 2; ++b) {
    const float* x1b = x1 + (size_t)b * PLANE;
    const float* x2b = x2 + (size_t)b * PLANE;
    float* ob = out + (size_t)b * PLANE;

    gemm_mfma<float, unsigned short><<<dim3(2, 512), dim3(256), 0, stream>>>(
        x1b, nullptr, qkvw, 0, qb);
    gemm_mfma<float, unsigned short><<<dim3(2, 512), dim3(256), 0, stream>>>(
        x2b, nullptr, qkvw, 256, kb);
    gemm_mfma<float, unsigned short><<<dim3(2, 512), dim3(256), 0, stream>>>(
        x1b, x2b, qkvw, 512, vd);
    win_colsum<<<dim3(1024), dim3(256), 0, stream>>>(x2b, S);
    v2s_gemm<<<dim3(1024), dim3(256), 0, stream>>>(S, qkvw, V2S);
    attn_win<<<dim3(1024, 16), dim3(64), 0, stream>>>(qb, kb, vd, V2S, relb, vd);
    pool_dir<<<dim3(8, 256), dim3(256), 0, stream>>>(vd, qb);   // P -> qb
    dwconv_bn<<<dim3(16, 256), dim3(256), 0, stream>>>(qb, dww, g, be, mn, vr, kb);
    gemm_mfma<unsigned short, float><<<dim3(2, 512), dim3(256), 0, stream>>>(
        kb, nullptr, pww, 0, ob);
  }
}

// Round 4
// 1150.079 us; speedup vs baseline: 1.2545x; 1.0611x over previous
//
#include <hip/hip_runtime.h>
#include <type_traits>

// ============================================================================
// CrossAttention pipeline, MI355X. Harness tensors are FP32; internal ws
// tensors are bf16. Geometry: B=2, C=256, H=W=256, NH=16, d=16, WS=8,
// hh=ww=32 -> 1024 windows/b.
// Identity: (attn@v1 + (1-attn)@v2)/2 = (attn@(v1-v2) + colsum(v2))/2
// R2 (1442.8us): MFMA GEMM w/ transposed-LDS X staging.
// R3 (1220.4us): band-tiled pool_dir; attn O bf16 in-place.
// R4: attn_win was top (175us x2, 471MB vs 130MB ideal -- plane layout makes
// every window access an 8x2B sliver; lines split across windows/XCDs).
//   - Q/K/VD now WINDOW-MAJOR [win][c][64] (win=(y>>3)*32+(x>>3),
//     i=(y&7)*8+(x&7)), written by the GEMM epilogue (WMOUT template arg).
//   - attn reads/writes become full-128B-line coalesced (base + dd*64 + lane);
//     O written in-place over VD in the same WM layout.
//   - pool_dir stages from WM: each 128B line = one (win,c) tile, fully
//     consumed per band block (<=24KB lines/block -> L1-resident reuse).
// ============================================================================

#define HW 65536     // H*W
#define WID 256

typedef __attribute__((ext_vector_type(8))) short short8;
typedef __attribute__((ext_vector_type(8))) unsigned short ushort8;
typedef __attribute__((ext_vector_type(4))) float f32x4;

__device__ __forceinline__ float b2f(unsigned short u) {
  union { unsigned int i; float f; } c; c.i = ((unsigned int)u) << 16; return c.f;
}
__device__ __forceinline__ unsigned short f2b(float f) {
  union { float ff; unsigned int i; } c; c.ff = f;
  return (unsigned short)((c.i + 0x7FFFu + ((c.i >> 16) & 1u)) >> 16);
}

// ----------------------------------------------------------------------------
// MFMA projection GEMM: Out[m,p] = sum_k W[w_row0+m,k] * A[k,p] (A opt A1-A2).
// A: [256][65536] (float or bf16). W fp32 ld=256 (bf16-rounded on stage).
// Out: plane [256][65536] (WMOUT=0) or window-major [win][m][64] (WMOUT=1).
// Grid: (2 m-tiles, 512 px-tiles), 256 thr. Tile 128m x 128px, BK=32,
// 4 waves as 2x2, each wave 64x64 = 4x4 frags of v_mfma_f32_16x16x32_bf16.
// ----------------------------------------------------------------------------
template <typename AT, typename OT, bool WMOUT>
__global__ __launch_bounds__(256) void gemm_mfma(
    const AT* __restrict__ A1, const AT* __restrict__ A2,
    const float* __restrict__ Wt, int w_row0, OT* __restrict__ Out) {
  __shared__ __align__(16) unsigned short Wl[128 * 40];  // [m][k] bf16, pad 40
  __shared__ __align__(16) unsigned short Xl[128 * 40];  // [px][k] bf16, pad 40

  const int t = threadIdx.x;
  const int l = t & 63;
  const int wv = t >> 6;               // wave 0..3
  const int wm  = (wv >> 1) * 64;      // wave m offset within tile
  const int wpx = (wv & 1) * 64;       // wave px offset within tile
  const int m0  = blockIdx.x * 128;    // m tile (fastest -> X tile L2 reuse)
  const int hw0 = blockIdx.y * 128;    // pixel tile (half of one image row)

  f32x4 acc[4][4];
#pragma unroll
  for (int a = 0; a < 4; ++a)
#pragma unroll
    for (int b = 0; b < 4; ++b) acc[a][b] = 0.f;

  const int sk  = t >> 3;              // 0..31
  const int spx = (t & 7) * 16;        // 0..112
  const int al  = l & 15;
  const int ak8 = (l >> 4) * 8;

  for (int k0 = 0; k0 < 256; k0 += 32) {
    // ---- stage X tile transposed (fp32 -> bf16, optionally A1-A2) ----
    {
      const size_t goff = (size_t)(k0 + sk) * HW + hw0 + spx;
      if constexpr (std::is_same_v<AT, float>) {
        const float4* p1 = (const float4*)(A1 + goff);
        float4 u0 = p1[0], u1 = p1[1], u2 = p1[2], u3 = p1[3];
        if (A2) {
          const float4* p2 = (const float4*)(A2 + goff);
          float4 w0 = p2[0], w1 = p2[1], w2 = p2[2], w3 = p2[3];
          u0.x -= w0.x; u0.y -= w0.y; u0.z -= w0.z; u0.w -= w0.w;
          u1.x -= w1.x; u1.y -= w1.y; u1.z -= w1.z; u1.w -= w1.w;
          u2.x -= w2.x; u2.y -= w2.y; u2.z -= w2.z; u2.w -= w2.w;
          u3.x -= w3.x; u3.y -= w3.y; u3.z -= w3.z; u3.w -= w3.w;
        }
        const float fa[16] = {u0.x, u0.y, u0.z, u0.w, u1.x, u1.y, u1.z, u1.w,
                              u2.x, u2.y, u2.z, u2.w, u3.x, u3.y, u3.z, u3.w};
#pragma unroll
        for (int i = 0; i < 16; ++i) Xl[(spx + i) * 40 + sk] = f2b(fa[i]);
      } else {
        const ushort8* p = (const ushort8*)(A1 + goff);
        ushort8 v0 = p[0], v1 = p[1];
#pragma unroll
        for (int i = 0; i < 8; ++i) {
          Xl[(spx + i) * 40 + sk]     = v0[i];
          Xl[(spx + 8 + i) * 40 + sk] = v1[i];
        }
      }
    }
    // ---- stage W tile (fp32 -> bf16), natural [m][k] ----
#pragma unroll
    for (int r = 0; r < 4; ++r) {
      const int idx = t + r * 256;
      const int row = idx >> 3;          // 0..127
      const int kq  = (idx & 7) * 4;     // 0..28
      float4 wv4 = *(const float4*)&Wt[(size_t)(w_row0 + m0 + row) * 256 + k0 + kq];
      unsigned short* d = &Wl[row * 40 + kq];
      d[0] = f2b(wv4.x); d[1] = f2b(wv4.y); d[2] = f2b(wv4.z); d[3] = f2b(wv4.w);
    }
    __syncthreads();

    short8 af[4], bf[4];
#pragma unroll
    for (int a = 0; a < 4; ++a)
      af[a] = *(const short8*)&Wl[(wm + a * 16 + al) * 40 + ak8];
#pragma unroll
    for (int b = 0; b < 4; ++b)
      bf[b] = *(const short8*)&Xl[(wpx + b * 16 + al) * 40 + ak8];
#pragma unroll
    for (int a = 0; a < 4; ++a)
#pragma unroll
      for (int b = 0; b < 4; ++b)
        acc[a][b] = __builtin_amdgcn_mfma_f32_16x16x32_bf16(
            af[a], bf[b], acc[a][b], 0, 0, 0);
    __syncthreads();
  }

  // ---- epilogue: D col(px) = lane&15, row(m) = (lane>>4)*4 + reg ----
  const int orow = m0 + wm + (l >> 4) * 4;
  if constexpr (WMOUT) {
    const int yq = hw0 >> 8;                 // image row of this tile
    const int wy = yq >> 3, iy = yq & 7;
    const int xbase = (hw0 & 255) + wpx + al;
#pragma unroll
    for (int a = 0; a < 4; ++a)
#pragma unroll
      for (int b = 0; b < 4; ++b) {
        const int x = xbase + b * 16;
        const size_t wb = ((size_t)(wy * 32 + (x >> 3)) * 256) * 64
                          + (size_t)(iy * 8 + (x & 7));
#pragma unroll
        for (int r = 0; r < 4; ++r)
          Out[wb + (size_t)(orow + a * 16 + r) * 64] = f2b(acc[a][b][r]);
      }
  } else {
    const int ocol = hw0 + wpx + al;
#pragma unroll
    for (int a = 0; a < 4; ++a)
#pragma unroll
      for (int b = 0; b < 4; ++b)
#pragma unroll
        for (int r = 0; r < 4; ++r) {
          const size_t o = (size_t)(orow + a * 16 + r) * HW + (ocol + b * 16);
          if constexpr (std::is_same_v<OT, float>) Out[o] = acc[a][b][r];
          else Out[o] = f2b(acc[a][b][r]);
        }
  }
}

// ----------------------------------------------------------------------------
// Window column-sums of x2 (fp32): S[c][wy][wx] = sum over 8x8 window.
// ----------------------------------------------------------------------------
__global__ __launch_bounds__(256) void win_colsum(
    const float* __restrict__ X2, float* __restrict__ S) {
  int idx = blockIdx.x * 256 + threadIdx.x;   // 262144 per batch item
  int wx = idx & 31, wy = (idx >> 5) & 31, c = idx >> 10;
  const float* base = X2 + (size_t)c * HW + (size_t)(wy * 8) * WID + wx * 8;
  float s = 0.f;
#pragma unroll
  for (int iy = 0; iy < 8; ++iy) {
    float4 u0 = *(const float4*)(base + iy * WID);
    float4 u1 = *(const float4*)(base + iy * WID + 4);
    s += u0.x + u0.y + u0.z + u0.w + u1.x + u1.y + u1.z + u1.w;
  }
  S[idx] = s;
}

// ----------------------------------------------------------------------------
// V2S[w][c] = sum_k Wv[c,k] * S[k][w]  (Wv = qkv_w rows 512..767, fp32)
// ----------------------------------------------------------------------------
__global__ __launch_bounds__(256) void v2s_gemm(
    const float* __restrict__ S, const float* __restrict__ Wt,
    float* __restrict__ V2S) {
  __shared__ float sv[256];
  int wpos = blockIdx.x;          // 0..1023
  int c = threadIdx.x;
  sv[c] = S[(size_t)c * 1024 + wpos];
  __syncthreads();
  const float* wr = Wt + (size_t)(512 + c) * 256;
  float acc = 0.f;
#pragma unroll 4
  for (int k = 0; k < 256; k += 8) {
    float4 a = *(const float4*)&wr[k];
    float4 b = *(const float4*)&wr[k + 4];
    acc += a.x * sv[k]     + a.y * sv[k + 1]
         + a.z * sv[k + 2] + a.w * sv[k + 3]
         + b.x * sv[k + 4] + b.y * sv[k + 5]
         + b.z * sv[k + 6] + b.w * sv[k + 7];
  }
  V2S[(size_t)wpos * 256 + c] = acc;
}

// ----------------------------------------------------------------------------
// Windowed attention, one wave per (window, head). Lane = query position i.
// Q/K/VD window-major bf16 [win][c][64]; O bf16 same layout, IN-PLACE over VD
// (thread i writes exactly the addresses it read; cross-thread values only
// flow through LDS staged before __syncthreads; blocks own disjoint regions).
// o[i,dd] = 0.5 * (sum_j softmax(q.k*0.25 + bias)[j] * vd[j,dd] + v2sum[dd])
// ----------------------------------------------------------------------------
__global__ __launch_bounds__(64) void attn_win(
    const unsigned short* __restrict__ Q, const unsigned short* __restrict__ K,
    const unsigned short* VD, const float* __restrict__ V2S,
    const float* __restrict__ RB, unsigned short* O) {
  __shared__ __align__(16) float4 ks4[64][5];  // 5th float4 pads row to 80 B
  __shared__ __align__(16) float4 vs4[64][5];
  __shared__ float bs[225];
  __shared__ float v2l[16];
  const int n = blockIdx.x;        // window 0..1023
  const int h = blockIdx.y;        // head
  const int i = threadIdx.x;       // query position (lane)
  const int iy = i >> 3, ix = i & 7;
  const size_t base = ((size_t)n * 256 + h * 16) * 64;   // 16 ch x 64 px

  float q[16];
#pragma unroll
  for (int q4 = 0; q4 < 4; ++q4) {
    float4 kv, vv;
    kv.x = b2f(K[base + (q4 * 4 + 0) * 64 + i]);
    kv.y = b2f(K[base + (q4 * 4 + 1) * 64 + i]);
    kv.z = b2f(K[base + (q4 * 4 + 2) * 64 + i]);
    kv.w = b2f(K[base + (q4 * 4 + 3) * 64 + i]);
    vv.x = b2f(VD[base + (q4 * 4 + 0) * 64 + i]);
    vv.y = b2f(VD[base + (q4 * 4 + 1) * 64 + i]);
    vv.z = b2f(VD[base + (q4 * 4 + 2) * 64 + i]);
    vv.w = b2f(VD[base + (q4 * 4 + 3) * 64 + i]);
    q[q4 * 4 + 0] = b2f(Q[base + (q4 * 4 + 0) * 64 + i]);
    q[q4 * 4 + 1] = b2f(Q[base + (q4 * 4 + 1) * 64 + i]);
    q[q4 * 4 + 2] = b2f(Q[base + (q4 * 4 + 2) * 64 + i]);
    q[q4 * 4 + 3] = b2f(Q[base + (q4 * 4 + 3) * 64 + i]);
    ks4[i][q4] = kv; vs4[i][q4] = vv;
  }
  for (int r = i; r < 225; r += 64) bs[r] = RB[r * 16 + h];
  if (i < 16) v2l[i] = V2S[(size_t)n * 256 + h * 16 + i];
  __syncthreads();

  float dots[64];
  float mx = -1e30f;
#pragma unroll
  for (int j = 0; j < 64; ++j) {
    const int jy = j >> 3, jx = j & 7;
    float s = 0.f;
#pragma unroll
    for (int q4 = 0; q4 < 4; ++q4) {
      float4 kv = ks4[j][q4];
      s = fmaf(q[q4 * 4 + 0], kv.x, s); s = fmaf(q[q4 * 4 + 1], kv.y, s);
      s = fmaf(q[q4 * 4 + 2], kv.z, s); s = fmaf(q[q4 * 4 + 3], kv.w, s);
    }
    s = s * 0.25f + bs[(iy - jy + 7) * 15 + (ix - jx + 7)];
    dots[j] = s; mx = fmaxf(mx, s);
  }
  float sum = 0.f;
#pragma unroll
  for (int j = 0; j < 64; ++j) { float e = __expf(dots[j] - mx); dots[j] = e; sum += e; }
  const float inv = 1.0f / sum;
  float o[16];
#pragma unroll
  for (int dd = 0; dd < 16; ++dd) o[dd] = v2l[dd];
#pragma unroll
  for (int j = 0; j < 64; ++j) {
    float p = dots[j] * inv;
#pragma unroll
    for (int q4 = 0; q4 < 4; ++q4) {
      float4 vv = vs4[j][q4];
      o[q4 * 4 + 0] = fmaf(p, vv.x, o[q4 * 4 + 0]);
      o[q4 * 4 + 1] = fmaf(p, vv.y, o[q4 * 4 + 1]);
      o[q4 * 4 + 2] = fmaf(p, vv.z, o[q4 * 4 + 2]);
      o[q4 * 4 + 3] = fmaf(p, vv.w, o[q4 * 4 + 3]);
    }
  }
#pragma unroll
  for (int dd = 0; dd < 16; ++dd)
    O[base + dd * 64 + i] = f2b(0.5f * o[dd]);
}

// ----------------------------------------------------------------------------
// Directional pooling, band-tiled: block = (32-row band, channel). Input O is
// WINDOW-MAJOR bf16 [win][c][64]; stage <=39 halo rows once into LDS as f32
// (each (wy,wx,c) 128B line fully consumed within the block -> L1-resident).
// ax: 8x1 sum over rows y-3..y+4, zero outside [0,256], reflect 256->254.
// ay: 1x8 sum over cols, same rule. P[c][257][257] bf16, last row/col zero.
// ----------------------------------------------------------------------------
__global__ __launch_bounds__(256) void pool_dir(
    const unsigned short* __restrict__ O, unsigned short* __restrict__ P) {
  __shared__ float tile[39][256];
  const int bnd = blockIdx.x;     // 0..7 (32-row band)
  const int c = blockIdx.y;       // 0..255
  const int x = threadIdx.x;      // 0..255
  const int y0 = bnd * 32;
  const int r0 = (y0 >= 3) ? y0 - 3 : 0;
  const int rmax = (y0 + 35 <= 255) ? (y0 + 35) : 255;
  const int nrows = rmax - r0 + 1;          // <= 39
  for (int idx = threadIdx.x; idx < nrows * 32; idx += 256) {
    const int r = idx >> 5, wx = idx & 31;
    const int y = r0 + r;
    const int wy = y >> 3, iy = y & 7;
    const unsigned short* src = O + ((size_t)(wy * 32 + wx) * 256 + c) * 64 + iy * 8;
    ushort8 v = *(const ushort8*)src;
    float4 f0 = make_float4(b2f(v[0]), b2f(v[1]), b2f(v[2]), b2f(v[3]));
    float4 f1 = make_float4(b2f(v[4]), b2f(v[5]), b2f(v[6]), b2f(v[7]));
    *(float4*)&tile[r][wx * 8] = f0;
    *(float4*)&tile[r][wx * 8 + 4] = f1;
  }
  __syncthreads();
  unsigned short* prow = P + ((size_t)c * 257 + y0) * 257;
  for (int yy = 0; yy < 32; ++yy) {
    const int y = y0 + yy;
    float ax = 0.f;
#pragma unroll
    for (int u = -3; u <= 4; ++u) {
      int t = y + u;                         // uniform across wave
      if (t >= 0 && t <= 256) { int ph = (t == 256) ? 254 : t; ax += tile[ph - r0][x]; }
    }
    float ay = 0.f;
    const float* row = &tile[y - r0][0];
#pragma unroll
    for (int u = -3; u <= 4; ++u) {
      int t = x + u;
      if (t >= 0 && t <= 256) { int xx = (t == 256) ? 254 : t; ay += row[xx]; }
    }
    prow[x] = f2b(0.125f * (ax + ay));
    if (x == 0) prow[256] = 0;
    prow += 257;
  }
  if (bnd == 7) {                            // zero row y = 256
    unsigned short* zr = P + ((size_t)c * 257 + 256) * 257;
    zr[x] = 0;
    if (x == 0) zr[256] = 0;
  }
}

// ----------------------------------------------------------------------------
// 8x8 depthwise conv (pad 3, zero) over P [c][257][257] bf16 + BN -> bf16 out.
// 64x64 output tile per block, input tile (71x71 + halo) staged in LDS.
// ----------------------------------------------------------------------------
__global__ __launch_bounds__(256) void dwconv_bn(
    const unsigned short* __restrict__ P, const float* __restrict__ DW,
    const float* __restrict__ G, const float* __restrict__ Bt,
    const float* __restrict__ Mn, const float* __restrict__ Vr,
    unsigned short* __restrict__ Out) {
  __shared__ float tile[71 * 72];
  __shared__ float wk[64];
  const int c = blockIdx.y;
  const int ty = (blockIdx.x >> 2) * 64, tx = (blockIdx.x & 3) * 64;
  const int t = threadIdx.x;
  if (t < 64) wk[t] = DW[c * 64 + t];
  const unsigned short* pp = P + (size_t)c * 66049;
  for (int e = t; e < 71 * 71; e += 256) {
    int iy = e / 71, ixx = e - iy * 71;
    int gy = ty + iy - 3, gx = tx + ixx - 3;
    float v = 0.f;
    if (gy >= 0 && gy < 257 && gx >= 0 && gx < 257) v = b2f(pp[(size_t)gy * 257 + gx]);
    tile[iy * 72 + ixx] = v;
  }
  __syncthreads();
  const int ox0 = (t & 15) * 4, oy0 = (t >> 4) * 4;
  float acc[4][4];
#pragma unroll
  for (int r = 0; r < 4; ++r)
#pragma unroll
    for (int cc = 0; cc < 4; ++cc) acc[r][cc] = 0.f;
  for (int ky = 0; ky < 8; ++ky) {
#pragma unroll
    for (int r = 0; r < 4; ++r) {
      const float* row = &tile[(oy0 + r + ky) * 72 + ox0];
      float rv[11];
#pragma unroll
      for (int u = 0; u < 11; ++u) rv[u] = row[u];
#pragma unroll
      for (int kx = 0; kx < 8; ++kx) {
        float wv = wk[ky * 8 + kx];
        acc[r][0] = fmaf(rv[kx + 0], wv, acc[r][0]);
        acc[r][1] = fmaf(rv[kx + 1], wv, acc[r][1]);
        acc[r][2] = fmaf(rv[kx + 2], wv, acc[r][2]);
        acc[r][3] = fmaf(rv[kx + 3], wv, acc[r][3]);
      }
    }
  }
  const float inv = G[c] * rsqrtf(Vr[c] + 1e-5f);
  const float mu = Mn[c], bb = Bt[c];
#pragma unroll
  for (int r = 0; r < 4; ++r) {
    unsigned short* dst = Out + (size_t)c * HW + (size_t)(ty + oy0 + r) * WID + (tx + ox0);
#pragma unroll
    for (int cc = 0; cc < 4; ++cc) dst[cc] = f2b((acc[r][cc] - mu) * inv + bb);
  }
}

// ----------------------------------------------------------------------------
extern "C" void kernel_launch(void* const* d_in, const int* in_sizes, int n_in,
                              void* d_out, int out_size, void* d_ws, size_t ws_size,
                              hipStream_t stream) {
  const float* x1   = (const float*)d_in[0];
  const float* x2   = (const float*)d_in[1];
  const float* qkvw = (const float*)d_in[2];
  const float* relb = (const float*)d_in[3];
  const float* dww  = (const float*)d_in[4];
  const float* g    = (const float*)d_in[5];
  const float* be   = (const float*)d_in[6];
  const float* mn   = (const float*)d_in[7];
  const float* vr   = (const float*)d_in[8];
  const float* pww  = (const float*)d_in[9];
  float* out = (float*)d_out;

  const size_t PLANE = (size_t)256 * HW;
  // ws layout (bf16 intermediates, reused per batch item sequentially):
  //   vd/O [16777216] | qb/P [16908544] | kb/dcbn [16777216] | S,V2S f32
  unsigned short* vd = (unsigned short*)d_ws;  // v1-v2 (WM), then attn O (WM)
  unsigned short* qb = vd + 16777216;          // q (WM), later pooled P
  unsigned short* kb = qb + 16908544;          // k (WM), later dwconv+BN out
  float* S   = (float*)(kb + 16777216);
  float* V2S = S + 262144;

  for (int b = 0; b < 2; ++b) {
    const float* x1b = x1 + (size_t)b * PLANE;
    const float* x2b = x2 + (size_t)b * PLANE;
    float* ob = out + (size_t)b * PLANE;

    gemm_mfma<float, unsigned short, true><<<dim3(2, 512), dim3(256), 0, stream>>>(
        x1b, nullptr, qkvw, 0, qb);
    gemm_mfma<float, unsigned short, true><<<dim3(2, 512), dim3(256), 0, stream>>>(
        x2b, nullptr, qkvw, 256, kb);
    gemm_mfma<float, unsigned short, true><<<dim3(2, 512), dim3(256), 0, stream>>>(
        x1b, x2b, qkvw, 512, vd);
    win_colsum<<<dim3(1024), dim3(256), 0, stream>>>(x2b, S);
    v2s_gemm<<<dim3(1024), dim3(256), 0, stream>>>(S, qkvw, V2S);
    attn_win<<<dim3(1024, 16), dim3(64), 0, stream>>>(qb, kb, vd, V2S, relb, vd);
    pool_dir<<<dim3(8, 256), dim3(256), 0, stream>>>(vd, qb);   // P -> qb
    dwconv_bn<<<dim3(16, 256), dim3(256), 0, stream>>>(qb, dww, g, be, mn, vr, kb);
    gemm_mfma<unsigned short, float, false><<<dim3(2, 512), dim3(256), 0, stream>>>(
        kb, nullptr, pww, 0, ob);
  }
}